// Round 19
// baseline (96.262 us; speedup 1.0000x reference)
//
#include <hip/hip_runtime.h>

typedef __attribute__((ext_vector_type(4))) int   v4i;
typedef __attribute__((ext_vector_type(8))) short s8;     // 8 bf16
typedef __attribute__((ext_vector_type(4))) float f32x4;
typedef __attribute__((ext_vector_type(16))) float f32x16;

#define GLB __attribute__((address_space(1)))
#define LDS_AS __attribute__((address_space(3)))

__device__ __forceinline__ unsigned short f2bf(float f) {
  unsigned u = __builtin_bit_cast(unsigned, f);
  return (unsigned short)((u + 0x7fffu + ((u >> 16) & 1u)) >> 16);   // RNE
}

// ---- merged prep. Blocks 0..2047: x f32 NCHW -> padded NHWC bf16 [32][66][66][128]
//      Blocks 2048..3199: weight -> fragment-major bf16 ww[tap][c][cog][kk][lane][e]
__global__ void prep(const float* __restrict__ x, const float* __restrict__ w,
                     unsigned int* __restrict__ xw, unsigned short* __restrict__ ww) {
  int t = threadIdx.x;
  if (blockIdx.x >= 2048) {                          // ---- weight part
    int o = (blockIdx.x - 2048) * 256 + t;           // 0..294911 exact
    int tap = o >> 15;
    int c   = (o >> 13) & 3;
    int cog = (o >> 10) & 7;
    int kk  = (o >> 9) & 1;
    int lh  = (o >> 8) & 1;
    int l31 = (o >> 3) & 31;
    int e   = o & 7;
    int co = cog * 32 + l31;
    int ci = c * 32 + kk * 16 + lh * 8 + e;
    ww[o] = f2bf(w[(co * 128 + ci) * 9 + tap]);
    return;
  }
  __shared__ float tile[128][65];
  int bid = blockIdx.x;                              // b*64 + h
  int b = bid >> 6, h = bid & 63;
  {
    // vectorized: 8 x float4 per thread (16B/lane, 4KB/wave-instr, coalesced)
    int wcol4 = (t & 15) * 4, cl = t >> 4;
    const float* src = x + ((size_t)(b * 128) * 64 + h) * 64 + wcol4;
#pragma unroll
    for (int j = 0; j < 8; ++j) {
      int ci = j * 16 + cl;
      f32x4 v = *(const f32x4*)(src + (size_t)ci * 4096);
      tile[ci][wcol4 + 0] = v[0];                    // 2 lanes/bank: free
      tile[ci][wcol4 + 1] = v[1];
      tile[ci][wcol4 + 2] = v[2];
      tile[ci][wcol4 + 3] = v[3];
    }
  }
  unsigned int* dst = xw + (size_t)((b * 66 + h + 1) * 66) * 64;   // 64 dwords/pixel
  if (t < 128) {                                     // pad cols 0 / 65 of this row
    int col = (t >> 6) ? 65 : 0;
    dst[(size_t)col * 64 + (t & 63)] = 0u;
  }
  if (h == 0 || h == 63) {                           // pad rows 0 / 65 of this batch
    unsigned int* rb = xw + (size_t)(b * 66 + (h == 0 ? 0 : 65)) * 66 * 64;
    for (int j = t; j < 66 * 64; j += 256) rb[j] = 0u;
  }
  __syncthreads();
  {
    int ci2 = (t & 63) * 2, wl = t >> 6;
#pragma unroll
    for (int j = 0; j < 16; ++j) {
      int wcol = j * 4 + wl;
      unsigned p = (unsigned)f2bf(tile[ci2][wcol]) |
                   ((unsigned)f2bf(tile[ci2 + 1][wcol]) << 16);
      dst[(size_t)(wcol + 1) * 64 + (t & 63)] = p;
    }
  }
}

// ---- main: implicit GEMM. Block = 256co x 64pix (1 h-row), 4 waves (co-split),
//      wave = 64co x 64pix. Stage all 128 ci once (52.2 KB). Barrier-free MFMA
//      stream with uncollapsible asm A-ring (vmcnt-counted, 2 steps ahead)
//      AND asm B-ring (lgkmcnt-counted ds_read_b128, 1 step ahead).
//      r18 A/B: setprio removed -> conv 76.6->74.2 (kept).
//      r19 A/B: XCD swizzle REMOVED (L3-fit regime: swizzle spreads h-adjacent
//      blocks' shared halo rows across XCD L2s; m160 analog says it costs ~2%).
__global__ __launch_bounds__(256, 3) void conv_mfma(
    const unsigned short* __restrict__ xw, const unsigned short* __restrict__ ww,
    const float* __restrict__ bias, float* __restrict__ out) {
  // LDS: 204 pixels (3 pad-rows x 68 cols) x 16 units x 16B.
  // unit u of pixel q stored at position u ^ (q&15)  (bank swizzle, involution)
  __shared__ unsigned short Xl[204 * 128];           // 52,224 B
  const int tid = threadIdx.x;
  const int lane = tid & 63;
  const int l31 = lane & 31, lh = lane >> 5;
  const int mw = tid >> 6;                           // wave = co group of 64
  const int bid = blockIdx.x;                        // natural order (no swizzle)
  const int b = bid >> 6, h0 = bid & 63;
  const unsigned xlb = (unsigned)(unsigned long long)((LDS_AS void*)Xl);

  // ---- single-shot stage: 3264 16B units, coalesced source, linear LDS dest
  {
    const char* xbase = (const char*)xw;
#pragma unroll
    for (int it = 0; it < 13; ++it) {
      int s = tid + it * 256;
      if (s < 3264) {
        int q = s >> 4, p = s & 15;
        int u = p ^ (q & 15);
        int rr = q / 68, cc = q - rr * 68;
        if (cc > 65) cc = 65;                        // junk slots: in-bounds addr
        unsigned src = (unsigned)((b * 66 + h0 + rr) * 66 + cc) * 256u + (unsigned)u * 16u;
        __builtin_amdgcn_global_load_lds((const GLB unsigned int*)(xbase + src),
                                         (LDS_AS unsigned int*)&Xl[s * 8], 16, 0, 0);
      }
    }
  }

  f32x16 acc[2][2];
#pragma unroll
  for (int m = 0; m < 2; ++m)
#pragma unroll
    for (int n = 0; n < 2; ++n)
#pragma unroll
      for (int e = 0; e < 16; ++e) acc[m][n][e] = 0.f;

  // A ring: 3 slots x 4 fragments (m0k0,m0k1,m1k0,m1k1), issued 2 steps ahead.
  v4i areg[3][4];
  // B ring: 2 slots x 4 fragments {q0k0,q1k0,q0k1,q1k1}, issued 1 step ahead.
  v4i breg[2][4];
  const unsigned abyte = (unsigned)(mw * 4096 + lane * 16);

  #define ALOAD_ASM(slot, step)                                               \
    do {                                                                      \
      unsigned _wo = (unsigned)(step) * 16384u + abyte;                       \
      asm volatile("global_load_dwordx4 %0, %1, %2 offset:0"                  \
                   : "=v"(areg[slot][0]) : "v"(_wo), "s"(ww));                \
      asm volatile("global_load_dwordx4 %0, %1, %2 offset:1024"               \
                   : "=v"(areg[slot][1]) : "v"(_wo), "s"(ww));                \
      asm volatile("global_load_dwordx4 %0, %1, %2 offset:2048"               \
                   : "=v"(areg[slot][2]) : "v"(_wo), "s"(ww));                \
      asm volatile("global_load_dwordx4 %0, %1, %2 offset:3072"               \
                   : "=v"(areg[slot][3]) : "v"(_wo), "s"(ww));                \
    } while (0)

  // B fragments for step (tap = S>>2, c = S&3) from swizzled LDS, via asm
  #define BLOAD_ASM(slot, S)                                                  \
    do {                                                                      \
      const int _t = (S) >> 2, _c = (S) & 3;                                  \
      const int _kh = _t / 3, _kw = _t - _kh * 3;                             \
      const int _q0 = _kh * 68 + _kw + l31;                                   \
      const int _xq = (_q0 & 15) ^ lh;      /* (q1&15)==(q0&15): +32 */       \
      unsigned _a0 = xlb + (unsigned)((_q0 << 8) + (((_c * 4) ^ _xq) << 4));  \
      unsigned _a1 = xlb + (unsigned)((_q0 << 8) + (((_c * 4 + 2) ^ _xq) << 4)); \
      asm volatile("ds_read_b128 %0, %1" : "=v"(breg[slot][0]) : "v"(_a0));   \
      asm volatile("ds_read_b128 %0, %1 offset:8192"                          \
                   : "=v"(breg[slot][1]) : "v"(_a0));                         \
      asm volatile("ds_read_b128 %0, %1" : "=v"(breg[slot][2]) : "v"(_a1));   \
      asm volatile("ds_read_b128 %0, %1 offset:8192"                          \
                   : "=v"(breg[slot][3]) : "v"(_a1));                         \
    } while (0)

  // one schedule step: issue A(s+2), B(s+1); counted wait; 8 MFMAs
  #define KSTEP(S)                                                            \
    do {                                                                      \
      const int _s = (S);                                                     \
      if (_s < 34) ALOAD_ASM((_s + 2) % 3, _s + 2);                           \
      if (_s < 35) BLOAD_ASM((_s + 1) & 1, _s + 1);                           \
      if (_s < 34)                                                            \
        asm volatile("s_waitcnt vmcnt(8) lgkmcnt(4)" ::: "memory");           \
      else if (_s == 34)                                                      \
        asm volatile("s_waitcnt vmcnt(4) lgkmcnt(4)" ::: "memory");           \
      else                                                                    \
        asm volatile("s_waitcnt vmcnt(0) lgkmcnt(0)" ::: "memory");           \
      __builtin_amdgcn_sched_barrier(0);                                      \
      const int _cs = _s % 3, _bs = _s & 1;                                   \
      acc[0][0] = __builtin_amdgcn_mfma_f32_32x32x16_bf16(__builtin_bit_cast(s8, areg[_cs][0]), __builtin_bit_cast(s8, breg[_bs][0]), acc[0][0], 0, 0, 0); \
      acc[1][0] = __builtin_amdgcn_mfma_f32_32x32x16_bf16(__builtin_bit_cast(s8, areg[_cs][2]), __builtin_bit_cast(s8, breg[_bs][0]), acc[1][0], 0, 0, 0); \
      acc[0][1] = __builtin_amdgcn_mfma_f32_32x32x16_bf16(__builtin_bit_cast(s8, areg[_cs][0]), __builtin_bit_cast(s8, breg[_bs][1]), acc[0][1], 0, 0, 0); \
      acc[1][1] = __builtin_amdgcn_mfma_f32_32x32x16_bf16(__builtin_bit_cast(s8, areg[_cs][2]), __builtin_bit_cast(s8, breg[_bs][1]), acc[1][1], 0, 0, 0); \
      acc[0][0] = __builtin_amdgcn_mfma_f32_32x32x16_bf16(__builtin_bit_cast(s8, areg[_cs][1]), __builtin_bit_cast(s8, breg[_bs][2]), acc[0][0], 0, 0, 0); \
      acc[1][0] = __builtin_amdgcn_mfma_f32_32x32x16_bf16(__builtin_bit_cast(s8, areg[_cs][3]), __builtin_bit_cast(s8, breg[_bs][2]), acc[1][0], 0, 0, 0); \
      acc[0][1] = __builtin_amdgcn_mfma_f32_32x32x16_bf16(__builtin_bit_cast(s8, areg[_cs][1]), __builtin_bit_cast(s8, breg[_bs][3]), acc[0][1], 0, 0, 0); \
      acc[1][1] = __builtin_amdgcn_mfma_f32_32x32x16_bf16(__builtin_bit_cast(s8, areg[_cs][3]), __builtin_bit_cast(s8, breg[_bs][3]), acc[1][1], 0, 0, 0); \
    } while (0)

  // ---- prologue: prime A ring; wave-local stage drain; block sync; prime B
  ALOAD_ASM(0, 0);
  ALOAD_ASM(1, 1);
  asm volatile("s_waitcnt vmcnt(8)" ::: "memory");   // staging landed; A in flight
  __builtin_amdgcn_sched_barrier(0);
  __builtin_amdgcn_s_barrier();                      // all waves' stage visible
  BLOAD_ASM(0, 0);

#pragma unroll
  for (int s = 0; s < 36; ++s) KSTEP(s);

  // ---- epilogue: D row = (r&3) + 8*(r>>2) + 4*lh (co), col = l31 (pixel)
#pragma unroll
  for (int m = 0; m < 2; ++m)
#pragma unroll
    for (int rq = 0; rq < 4; ++rq) {
      const int cob = mw * 64 + m * 32 + 8 * rq + 4 * lh;
      const f32x4 bi = *(const f32x4*)(bias + cob);
#pragma unroll
      for (int n = 0; n < 2; ++n) {
        const int wc = n * 32 + l31;
        size_t base = ((size_t)(b * 256 + cob) * 64 + h0) * 64 + wc;
#pragma unroll
        for (int e = 0; e < 4; ++e)
          out[base + (size_t)e * 4096] = acc[m][n][rq * 4 + e] + bi[e];
      }
    }
}

// ---- fallback (ws too small): naive f32 conv, correct but slow
__global__ void conv_naive(const float* __restrict__ x, const float* __restrict__ w,
                           const float* __restrict__ bias, float* __restrict__ out) {
  int i = blockIdx.x * 256 + threadIdx.x;
  int wc = i & 63, h = (i >> 6) & 63, co = (i >> 12) & 255, b = i >> 20;
  float s = bias[co];
  for (int ci = 0; ci < 128; ++ci)
#pragma unroll
    for (int kh = 0; kh < 3; ++kh) {
      int hh = h + kh - 1;
      if ((unsigned)hh >= 64u) continue;
#pragma unroll
      for (int kw = 0; kw < 3; ++kw) {
        int wg = wc + kw - 1;
        if ((unsigned)wg >= 64u) continue;
        s += x[((b * 128 + ci) * 64 + hh) * 64 + wg] *
             w[((co * 128 + ci) * 3 + kh) * 3 + kw];
      }
    }
  out[i] = s;
}

extern "C" void kernel_launch(void* const* d_in, const int* in_sizes, int n_in,
                              void* d_out, int out_size, void* d_ws, size_t ws_size,
                              hipStream_t stream) {
  const float* x    = (const float*)d_in[0];
  const float* w    = (const float*)d_in[1];
  const float* bias = (const float*)d_in[2];
  float* out = (float*)d_out;

  const size_t X_OFF  = 1ull << 20;                            // ws_w in first 1 MB
  const size_t XBYTES = 32ull * 66 * 66 * 128 * 2;             // 35.7 MB padded NHWC
  const size_t NEED   = X_OFF + XBYTES;

  if (ws_size >= NEED) {
    unsigned short* ww = (unsigned short*)d_ws;
    unsigned short* xq = (unsigned short*)((char*)d_ws + X_OFF);
    hipLaunchKernelGGL(prep, dim3(3200), dim3(256), 0, stream, x, w,
                       (unsigned int*)xq, ww);
    hipLaunchKernelGGL(conv_mfma, dim3(2048), dim3(256), 0, stream, xq, ww, bias, out);
  } else {
    hipLaunchKernelGGL(conv_naive, dim3(131072), dim3(256), 0, stream, x, w, bias, out);
  }
}

// Round 20
// 93.308 us; speedup vs baseline: 1.0317x; 1.0317x over previous
//
#include <hip/hip_runtime.h>

typedef __attribute__((ext_vector_type(4))) int   v4i;
typedef __attribute__((ext_vector_type(8))) short s8;     // 8 bf16
typedef __attribute__((ext_vector_type(4))) float f32x4;
typedef __attribute__((ext_vector_type(16))) float f32x16;

#define GLB __attribute__((address_space(1)))
#define LDS_AS __attribute__((address_space(3)))

__device__ __forceinline__ unsigned short f2bf(float f) {
  unsigned u = __builtin_bit_cast(unsigned, f);
  return (unsigned short)((u + 0x7fffu + ((u >> 16) & 1u)) >> 16);   // RNE
}

// ---- merged prep. Blocks 0..2047: x f32 NCHW -> padded NHWC bf16 [32][66][66][128]
//      Blocks 2048..3199: weight -> fragment-major bf16 ww[tap][c][cog][kk][lane][e]
__global__ void prep(const float* __restrict__ x, const float* __restrict__ w,
                     unsigned int* __restrict__ xw, unsigned short* __restrict__ ww) {
  int t = threadIdx.x;
  if (blockIdx.x >= 2048) {                          // ---- weight part
    int o = (blockIdx.x - 2048) * 256 + t;           // 0..294911 exact
    int tap = o >> 15;
    int c   = (o >> 13) & 3;
    int cog = (o >> 10) & 7;
    int kk  = (o >> 9) & 1;
    int lh  = (o >> 8) & 1;
    int l31 = (o >> 3) & 31;
    int e   = o & 7;
    int co = cog * 32 + l31;
    int ci = c * 32 + kk * 16 + lh * 8 + e;
    ww[o] = f2bf(w[(co * 128 + ci) * 9 + tap]);
    return;
  }
  __shared__ float tile[128][65];
  int bid = blockIdx.x;                              // b*64 + h
  int b = bid >> 6, h = bid & 63;
  {
    // vectorized: 8 x float4 per thread (16B/lane, 4KB/wave-instr, coalesced)
    int wcol4 = (t & 15) * 4, cl = t >> 4;
    const float* src = x + ((size_t)(b * 128) * 64 + h) * 64 + wcol4;
#pragma unroll
    for (int j = 0; j < 8; ++j) {
      int ci = j * 16 + cl;
      f32x4 v = *(const f32x4*)(src + (size_t)ci * 4096);
      tile[ci][wcol4 + 0] = v[0];                    // 2 lanes/bank: free
      tile[ci][wcol4 + 1] = v[1];
      tile[ci][wcol4 + 2] = v[2];
      tile[ci][wcol4 + 3] = v[3];
    }
  }
  unsigned int* dst = xw + (size_t)((b * 66 + h + 1) * 66) * 64;   // 64 dwords/pixel
  if (t < 128) {                                     // pad cols 0 / 65 of this row
    int col = (t >> 6) ? 65 : 0;
    dst[(size_t)col * 64 + (t & 63)] = 0u;
  }
  if (h == 0 || h == 63) {                           // pad rows 0 / 65 of this batch
    unsigned int* rb = xw + (size_t)(b * 66 + (h == 0 ? 0 : 65)) * 66 * 64;
    for (int j = t; j < 66 * 64; j += 256) rb[j] = 0u;
  }
  __syncthreads();
  {
    int ci2 = (t & 63) * 2, wl = t >> 6;
#pragma unroll
    for (int j = 0; j < 16; ++j) {
      int wcol = j * 4 + wl;
      unsigned p = (unsigned)f2bf(tile[ci2][wcol]) |
                   ((unsigned)f2bf(tile[ci2 + 1][wcol]) << 16);
      dst[(size_t)(wcol + 1) * 64 + (t & 63)] = p;
    }
  }
}

// ---- main: implicit GEMM. Block = 256co x 64pix (1 h-row), 4 waves (co-split),
//      wave = 64co x 64pix. Stage all 128 ci once (52.2 KB). Barrier-free MFMA
//      stream with uncollapsible asm A-ring (vmcnt-counted, 2 steps ahead)
//      AND asm B-ring (lgkmcnt-counted ds_read_b128, 1 step ahead).
//      FINAL (session-best, = r18): setprio REMOVED (r18 A/B: 76.6->74.2, m190
//      analog — setprio hurts same-phase schedules); XCD swizzle PRESENT (r19
//      A/B: removing it tripled FETCH 20->54.5 MB, conv +1.5 us — contiguous
//      bid range per XCD keeps h-adjacent halos in one L2).
__global__ __launch_bounds__(256, 3) void conv_mfma(
    const unsigned short* __restrict__ xw, const unsigned short* __restrict__ ww,
    const float* __restrict__ bias, float* __restrict__ out) {
  // LDS: 204 pixels (3 pad-rows x 68 cols) x 16 units x 16B.
  // unit u of pixel q stored at position u ^ (q&15)  (bank swizzle, involution)
  __shared__ unsigned short Xl[204 * 128];           // 52,224 B
  const int tid = threadIdx.x;
  const int lane = tid & 63;
  const int l31 = lane & 31, lh = lane >> 5;
  const int mw = tid >> 6;                           // wave = co group of 64
  int bid = blockIdx.x;
  bid = (bid & 7) * 256 + (bid >> 3);                // XCD swizzle (2048%8==0)
  const int b = bid >> 6, h0 = bid & 63;
  const unsigned xlb = (unsigned)(unsigned long long)((LDS_AS void*)Xl);

  // ---- single-shot stage: 3264 16B units, coalesced source, linear LDS dest
  {
    const char* xbase = (const char*)xw;
#pragma unroll
    for (int it = 0; it < 13; ++it) {
      int s = tid + it * 256;
      if (s < 3264) {
        int q = s >> 4, p = s & 15;
        int u = p ^ (q & 15);
        int rr = q / 68, cc = q - rr * 68;
        if (cc > 65) cc = 65;                        // junk slots: in-bounds addr
        unsigned src = (unsigned)((b * 66 + h0 + rr) * 66 + cc) * 256u + (unsigned)u * 16u;
        __builtin_amdgcn_global_load_lds((const GLB unsigned int*)(xbase + src),
                                         (LDS_AS unsigned int*)&Xl[s * 8], 16, 0, 0);
      }
    }
  }

  f32x16 acc[2][2];
#pragma unroll
  for (int m = 0; m < 2; ++m)
#pragma unroll
    for (int n = 0; n < 2; ++n)
#pragma unroll
      for (int e = 0; e < 16; ++e) acc[m][n][e] = 0.f;

  // A ring: 3 slots x 4 fragments (m0k0,m0k1,m1k0,m1k1), issued 2 steps ahead.
  v4i areg[3][4];
  // B ring: 2 slots x 4 fragments {q0k0,q1k0,q0k1,q1k1}, issued 1 step ahead.
  v4i breg[2][4];
  const unsigned abyte = (unsigned)(mw * 4096 + lane * 16);

  #define ALOAD_ASM(slot, step)                                               \
    do {                                                                      \
      unsigned _wo = (unsigned)(step) * 16384u + abyte;                       \
      asm volatile("global_load_dwordx4 %0, %1, %2 offset:0"                  \
                   : "=v"(areg[slot][0]) : "v"(_wo), "s"(ww));                \
      asm volatile("global_load_dwordx4 %0, %1, %2 offset:1024"               \
                   : "=v"(areg[slot][1]) : "v"(_wo), "s"(ww));                \
      asm volatile("global_load_dwordx4 %0, %1, %2 offset:2048"               \
                   : "=v"(areg[slot][2]) : "v"(_wo), "s"(ww));                \
      asm volatile("global_load_dwordx4 %0, %1, %2 offset:3072"               \
                   : "=v"(areg[slot][3]) : "v"(_wo), "s"(ww));                \
    } while (0)

  // B fragments for step (tap = S>>2, c = S&3) from swizzled LDS, via asm
  #define BLOAD_ASM(slot, S)                                                  \
    do {                                                                      \
      const int _t = (S) >> 2, _c = (S) & 3;                                  \
      const int _kh = _t / 3, _kw = _t - _kh * 3;                             \
      const int _q0 = _kh * 68 + _kw + l31;                                   \
      const int _xq = (_q0 & 15) ^ lh;      /* (q1&15)==(q0&15): +32 */       \
      unsigned _a0 = xlb + (unsigned)((_q0 << 8) + (((_c * 4) ^ _xq) << 4));  \
      unsigned _a1 = xlb + (unsigned)((_q0 << 8) + (((_c * 4 + 2) ^ _xq) << 4)); \
      asm volatile("ds_read_b128 %0, %1" : "=v"(breg[slot][0]) : "v"(_a0));   \
      asm volatile("ds_read_b128 %0, %1 offset:8192"                          \
                   : "=v"(breg[slot][1]) : "v"(_a0));                         \
      asm volatile("ds_read_b128 %0, %1" : "=v"(breg[slot][2]) : "v"(_a1));   \
      asm volatile("ds_read_b128 %0, %1 offset:8192"                          \
                   : "=v"(breg[slot][3]) : "v"(_a1));                         \
    } while (0)

  // one schedule step: issue A(s+2), B(s+1); counted wait; 8 MFMAs
  #define KSTEP(S)                                                            \
    do {                                                                      \
      const int _s = (S);                                                     \
      if (_s < 34) ALOAD_ASM((_s + 2) % 3, _s + 2);                           \
      if (_s < 35) BLOAD_ASM((_s + 1) & 1, _s + 1);                           \
      if (_s < 34)                                                            \
        asm volatile("s_waitcnt vmcnt(8) lgkmcnt(4)" ::: "memory");           \
      else if (_s == 34)                                                      \
        asm volatile("s_waitcnt vmcnt(4) lgkmcnt(4)" ::: "memory");           \
      else                                                                    \
        asm volatile("s_waitcnt vmcnt(0) lgkmcnt(0)" ::: "memory");           \
      __builtin_amdgcn_sched_barrier(0);                                      \
      const int _cs = _s % 3, _bs = _s & 1;                                   \
      acc[0][0] = __builtin_amdgcn_mfma_f32_32x32x16_bf16(__builtin_bit_cast(s8, areg[_cs][0]), __builtin_bit_cast(s8, breg[_bs][0]), acc[0][0], 0, 0, 0); \
      acc[1][0] = __builtin_amdgcn_mfma_f32_32x32x16_bf16(__builtin_bit_cast(s8, areg[_cs][2]), __builtin_bit_cast(s8, breg[_bs][0]), acc[1][0], 0, 0, 0); \
      acc[0][1] = __builtin_amdgcn_mfma_f32_32x32x16_bf16(__builtin_bit_cast(s8, areg[_cs][0]), __builtin_bit_cast(s8, breg[_bs][1]), acc[0][1], 0, 0, 0); \
      acc[1][1] = __builtin_amdgcn_mfma_f32_32x32x16_bf16(__builtin_bit_cast(s8, areg[_cs][2]), __builtin_bit_cast(s8, breg[_bs][1]), acc[1][1], 0, 0, 0); \
      acc[0][0] = __builtin_amdgcn_mfma_f32_32x32x16_bf16(__builtin_bit_cast(s8, areg[_cs][1]), __builtin_bit_cast(s8, breg[_bs][2]), acc[0][0], 0, 0, 0); \
      acc[1][0] = __builtin_amdgcn_mfma_f32_32x32x16_bf16(__builtin_bit_cast(s8, areg[_cs][3]), __builtin_bit_cast(s8, breg[_bs][2]), acc[1][0], 0, 0, 0); \
      acc[0][1] = __builtin_amdgcn_mfma_f32_32x32x16_bf16(__builtin_bit_cast(s8, areg[_cs][1]), __builtin_bit_cast(s8, breg[_bs][3]), acc[0][1], 0, 0, 0); \
      acc[1][1] = __builtin_amdgcn_mfma_f32_32x32x16_bf16(__builtin_bit_cast(s8, areg[_cs][3]), __builtin_bit_cast(s8, breg[_bs][3]), acc[1][1], 0, 0, 0); \
    } while (0)

  // ---- prologue: prime A ring; wave-local stage drain; block sync; prime B
  ALOAD_ASM(0, 0);
  ALOAD_ASM(1, 1);
  asm volatile("s_waitcnt vmcnt(8)" ::: "memory");   // staging landed; A in flight
  __builtin_amdgcn_sched_barrier(0);
  __builtin_amdgcn_s_barrier();                      // all waves' stage visible
  BLOAD_ASM(0, 0);

#pragma unroll
  for (int s = 0; s < 36; ++s) KSTEP(s);

  // ---- epilogue: D row = (r&3) + 8*(r>>2) + 4*lh (co), col = l31 (pixel)
#pragma unroll
  for (int m = 0; m < 2; ++m)
#pragma unroll
    for (int rq = 0; rq < 4; ++rq) {
      const int cob = mw * 64 + m * 32 + 8 * rq + 4 * lh;
      const f32x4 bi = *(const f32x4*)(bias + cob);
#pragma unroll
      for (int n = 0; n < 2; ++n) {
        const int wc = n * 32 + l31;
        size_t base = ((size_t)(b * 256 + cob) * 64 + h0) * 64 + wc;
#pragma unroll
        for (int e = 0; e < 4; ++e)
          out[base + (size_t)e * 4096] = acc[m][n][rq * 4 + e] + bi[e];
      }
    }
}

// ---- fallback (ws too small): naive f32 conv, correct but slow
__global__ void conv_naive(const float* __restrict__ x, const float* __restrict__ w,
                           const float* __restrict__ bias, float* __restrict__ out) {
  int i = blockIdx.x * 256 + threadIdx.x;
  int wc = i & 63, h = (i >> 6) & 63, co = (i >> 12) & 255, b = i >> 20;
  float s = bias[co];
  for (int ci = 0; ci < 128; ++ci)
#pragma unroll
    for (int kh = 0; kh < 3; ++kh) {
      int hh = h + kh - 1;
      if ((unsigned)hh >= 64u) continue;
#pragma unroll
      for (int kw = 0; kw < 3; ++kw) {
        int wg = wc + kw - 1;
        if ((unsigned)wg >= 64u) continue;
        s += x[((b * 128 + ci) * 64 + hh) * 64 + wg] *
             w[((co * 128 + ci) * 3 + kh) * 3 + kw];
      }
    }
  out[i] = s;
}

extern "C" void kernel_launch(void* const* d_in, const int* in_sizes, int n_in,
                              void* d_out, int out_size, void* d_ws, size_t ws_size,
                              hipStream_t stream) {
  const float* x    = (const float*)d_in[0];
  const float* w    = (const float*)d_in[1];
  const float* bias = (const float*)d_in[2];
  float* out = (float*)d_out;

  const size_t X_OFF  = 1ull << 20;                            // ws_w in first 1 MB
  const size_t XBYTES = 32ull * 66 * 66 * 128 * 2;             // 35.7 MB padded NHWC
  const size_t NEED   = X_OFF + XBYTES;

  if (ws_size >= NEED) {
    unsigned short* ww = (unsigned short*)d_ws;
    unsigned short* xq = (unsigned short*)((char*)d_ws + X_OFF);
    hipLaunchKernelGGL(prep, dim3(3200), dim3(256), 0, stream, x, w,
                       (unsigned int*)xq, ww);
    hipLaunchKernelGGL(conv_mfma, dim3(2048), dim3(256), 0, stream, xq, ww, bias, out);
  } else {
    hipLaunchKernelGGL(conv_naive, dim3(131072), dim3(256), 0, stream, x, w, bias, out);
  }
}